// Round 10
// baseline (502.995 us; speedup 1.0000x reference)
//
#include <hip/hip_runtime.h>
#include <hip/hip_bf16.h>

typedef __attribute__((ext_vector_type(4))) float f32x4;
typedef __attribute__((ext_vector_type(8))) short bf16x8;

#define VOCAB 32000
#define DIMS 1024
#define BATCH 2
#define SEQ 2048
#define ROWS (BATCH * SEQ)  // 4096
#define NC 128              // cumsum chunks per sequence
#define CL 16               // chunk length; NC*CL == SEQ

// ---------- helpers ----------
static __device__ __forceinline__ unsigned short f2bf(float f) {
  unsigned int u = __float_as_uint(f);
  unsigned int r = u + 0x7fffu + ((u >> 16) & 1u);
  return (unsigned short)(r >> 16);
}

// ---------- fp32 -> bf16 bulk convert ----------
__global__ void cvt_f32_bf16(const float* __restrict__ src,
                             unsigned short* __restrict__ dst, int n4) {
  int i = blockIdx.x * blockDim.x + threadIdx.x;
  int stride = gridDim.x * blockDim.x;
  for (; i < n4; i += stride) {
    float4 v = ((const float4*)src)[i];
    ushort4 o = {f2bf(v.x), f2bf(v.y), f2bf(v.z), f2bf(v.w)};
    ((ushort4*)dst)[i] = o;
  }
}

// ---------- embedding gather + convert ----------
__global__ void gather_emb(const int* __restrict__ idx,
                           const float* __restrict__ emb,
                           unsigned short* __restrict__ eB) {
  const int row = blockIdx.x;
  const int t = threadIdx.x;
  const int token = idx[row];
  const float4* src = (const float4*)(emb + (size_t)token * DIMS);
  float4 v = src[t];
  ushort4 o = {f2bf(v.x), f2bf(v.y), f2bf(v.z), f2bf(v.w)};
  ((ushort4*)(eB + (size_t)row * DIMS))[t] = o;
}

// ---------- old 128x128 NT GEMM (kept for the small V projection) ----------
__global__ __launch_bounds__(256) void gemm_bt(
    const unsigned short* __restrict__ A, const unsigned short* __restrict__ B,
    float* __restrict__ C, const float* __restrict__ bias, int K, int ldC) {
  __shared__ __align__(16) unsigned short sA[128 * 32];
  __shared__ __align__(16) unsigned short sB[128 * 32];

  const int tid = threadIdx.x;
  const int lane = tid & 63;
  const int w = tid >> 6;
  const int wr = w >> 1;
  const int wc = w & 1;
  const long mBase = (long)blockIdx.x * 128;
  const long nBase = (long)blockIdx.y * 128;

  const unsigned short* Ati = A + mBase * K;
  const unsigned short* Bti = B + nBase * K;

  const int srow0 = w * 32;
  const int sr = lane >> 2;
  const int ske = (lane & 3) * 8;

  f32x4 acc[4][4] = {};

  for (int kt = 0; kt < K; kt += 32) {
    __syncthreads();
#pragma unroll
    for (int i = 0; i < 2; ++i) {
      const int r = srow0 + i * 16;
      __builtin_amdgcn_global_load_lds(
          (const __attribute__((address_space(1))) unsigned int*)(
              Ati + (long)(r + sr) * K + kt + ske),
          (__attribute__((address_space(3))) unsigned int*)(&sA[r * 32]),
          16, 0, 0);
      __builtin_amdgcn_global_load_lds(
          (const __attribute__((address_space(1))) unsigned int*)(
              Bti + (long)(r + sr) * K + kt + ske),
          (__attribute__((address_space(3))) unsigned int*)(&sB[r * 32]),
          16, 0, 0);
    }
    __syncthreads();

    bf16x8 af[4], bfr[4];
#pragma unroll
    for (int mi = 0; mi < 4; ++mi)
      af[mi] = *(const bf16x8*)&sA[(wr * 64 + mi * 16 + (lane & 15)) * 32 +
                                   8 * (lane >> 4)];
#pragma unroll
    for (int ni = 0; ni < 4; ++ni)
      bfr[ni] = *(const bf16x8*)&sB[(wc * 64 + ni * 16 + (lane & 15)) * 32 +
                                    8 * (lane >> 4)];
#pragma unroll
    for (int mi = 0; mi < 4; ++mi)
#pragma unroll
      for (int ni = 0; ni < 4; ++ni)
        acc[mi][ni] = __builtin_amdgcn_mfma_f32_16x16x32_bf16(
            af[mi], bfr[ni], acc[mi][ni], 0, 0, 0);
  }

  const int rq = lane >> 4;
  const int cl = lane & 15;
#pragma unroll
  for (int ni = 0; ni < 4; ++ni) {
    const long c = nBase + wc * 64 + ni * 16 + cl;
    const float bv = bias ? bias[c] : 0.0f;
#pragma unroll
    for (int mi = 0; mi < 4; ++mi) {
      const long r = mBase + wr * 64 + mi * 16 + rq * 4;
#pragma unroll
      for (int j = 0; j < 4; ++j)
        C[(r + j) * (long)ldC + c] = acc[mi][ni][j] + bv;
    }
  }
}

// ---------- 512x128 NT GEMM (big output projection) ----------
// ROUND 10: r4-r9 all flatline ~350us/33% MfmaUtil. Per-CU pipe sums for r8:
// MFMA 310k cyc + LDS 390k (frag reads 0.5 b128/MFMA + staging writes) +
// VALU 160k (address chains) ~= wall 840k -> pipes fully SERIALIZED (convoy:
// barriers phase-lock waves; all reads queue together, MFMAs tail after).
// This round cuts the serial SUM instead of fighting the convoy:
//  - wave-tile 128x64 (8 waves = 4m x 2n): reads/MFMA 0.5 -> 0.375 (floor
//    at feasible acc=128 regs). LDS read bytes 8.4 -> 6.3 GB.
//  - BM=512: B re-read M/BM = 8x (was 16x) -> FETCH down, B-L3 traffic halved.
//  - address hoisting: persistent per-lane global ptrs, += 64 B per window
//    (kills the per-window 64-bit mad chains; ds-read addrs fold to base+imm).
//  - LDS 2x(512+128)x32x2B = 80 KiB, 1 block/CU; BK=32; simplest window
//    schedule (r4-r9: schedule variants proven ~equivalent).
// Ledger (5 loads/wave/window: A 4 + B 1): steady outstanding entering t =
// {t, t+1} = 10 -> vmcnt(5) retires tile t. Tail t==NT-1: only tile NT-1's 5
// outstanding -> vmcnt(0) (vmcnt(5) would no-op -> race). Stage(t+2) after
// 2nd barrier into just-consumed buffer (WAR-safe, r8 pattern).
// Swizzle: r4-proven involution (conflicts measured 0 in r4-r9).
__global__ __launch_bounds__(512, 2) void gemm512x128_bt(
    const unsigned short* __restrict__ A,  // [M][K] bf16, K-contiguous
    const unsigned short* __restrict__ B,  // [N][K] bf16, K-contiguous
    float* __restrict__ C,                 // [M][ldC] fp32
    const float* __restrict__ bias,        // [>=N] fp32 or nullptr
    int K, int ldC) {
  __shared__ __align__(16) unsigned short lds[2][640 * 32];  // 80 KiB

  const int tid = threadIdx.x;
  const int lane = tid & 63;
  const int w = tid >> 6;  // wave 0..7
  const int wr = w >> 1;   // 0..3 -> A row-quarter (128 rows of 512)
  const int wc = w & 1;    // 0..1 -> B col-half (64 of 128)
  const long mBase = (long)blockIdx.x * 512;
  const long nBase = (long)blockIdx.y * 128;
  const int NT = K >> 5;  // BK=32 windows

  const int rl = lane & 15;
  const int koffR = ((lane >> 4) * 8) ^ (((rl >> 1) & 3) << 3);
  const int skel = ((lane & 3) * 8) ^ (((lane >> 3) & 3) << 3);

  // hoisted per-lane global source pointers (advance += 32 elems per window)
  const unsigned short* ap0 =
      A + (mBase + 0 + w * 16 + (lane >> 2)) * (long)K + skel;
  const unsigned short* ap1 =
      A + (mBase + 128 + w * 16 + (lane >> 2)) * (long)K + skel;
  const unsigned short* ap2 =
      A + (mBase + 256 + w * 16 + (lane >> 2)) * (long)K + skel;
  const unsigned short* ap3 =
      A + (mBase + 384 + w * 16 + (lane >> 2)) * (long)K + skel;
  const unsigned short* bp =
      B + (nBase + w * 16 + (lane >> 2)) * (long)K + skel;

#define GL(p, d)                                                       \
  __builtin_amdgcn_global_load_lds(                                    \
      (const __attribute__((address_space(1))) unsigned int*)(p),      \
      (__attribute__((address_space(3))) unsigned int*)(d), 16, 0, 0)
#define STAGE_ALL(buf)                          \
  do {                                          \
    GL(ap0, (buf) + (0 + w * 16) * 32);         \
    GL(ap1, (buf) + (128 + w * 16) * 32);       \
    GL(ap2, (buf) + (256 + w * 16) * 32);       \
    GL(ap3, (buf) + (384 + w * 16) * 32);       \
    GL(bp, (buf) + 16384 + w * 512);            \
    ap0 += 32; ap1 += 32; ap2 += 32; ap3 += 32; \
    bp += 32;                                   \
  } while (0)
#define LDF(pl, r) (*(const bf16x8*)&(pl)[(r) * 32 + koffR])

  f32x4 acc[8][4] = {};

  // ---- prologue: stage windows 0,1 (10 loads/wave outstanding) ----
  STAGE_ALL(lds[0]);
  STAGE_ALL(lds[1]);

#pragma unroll 2
  for (int t = 0; t < NT; ++t) {
    unsigned short* buf = lds[t & 1];
    const unsigned short* Ap = buf;          // [512][32]
    const unsigned short* Bp = buf + 16384;  // [128][32]

    if (t == NT - 1)
      asm volatile("s_waitcnt vmcnt(0)" ::: "memory");
    else
      asm volatile("s_waitcnt vmcnt(5)" ::: "memory");
    __builtin_amdgcn_s_barrier();

    bf16x8 a[8], b[4];
#pragma unroll
    for (int mi = 0; mi < 8; ++mi)
      a[mi] = LDF(Ap, wr * 128 + mi * 16 + rl);
#pragma unroll
    for (int ni = 0; ni < 4; ++ni) b[ni] = LDF(Bp, wc * 64 + ni * 16 + rl);

    __builtin_amdgcn_s_setprio(1);
#pragma unroll
    for (int mi = 0; mi < 8; ++mi)
#pragma unroll
      for (int ni = 0; ni < 4; ++ni)
        acc[mi][ni] = __builtin_amdgcn_mfma_f32_16x16x32_bf16(
            a[mi], b[ni], acc[mi][ni], 0, 0, 0);
    __builtin_amdgcn_s_setprio(0);
    __builtin_amdgcn_s_barrier();

    if (t + 2 < NT) STAGE_ALL(buf);
  }
#undef LDF
#undef STAGE_ALL
#undef GL

  // ---- epilogue: C/D frag mapping col=lane&15, row=4*(lane>>4)+reg [m89] ----
  const int rq = lane >> 4;
  const int cl = lane & 15;
#pragma unroll
  for (int ni = 0; ni < 4; ++ni) {
    const long c = nBase + wc * 64 + ni * 16 + cl;
    const float bv = bias ? bias[c] : 0.0f;
#pragma unroll
    for (int mi = 0; mi < 8; ++mi) {
      const long r = mBase + wr * 128 + mi * 16 + rq * 4;
#pragma unroll
      for (int j = 0; j < 4; ++j)
        C[(r + j) * (long)ldC + c] = acc[mi][ni][j] + bv;
    }
  }
}

// ---------- causal cumulative mean (chunked scan) ----------
__global__ void chunk_sums(const float* __restrict__ V,
                           float* __restrict__ part) {
  const int bc = blockIdx.x;
  const int b = bc >> 7;
  const int c = bc & (NC - 1);
  const int d0 = threadIdx.x * 4;
  const float* vp = V + ((size_t)b * SEQ + (size_t)c * CL) * DIMS + d0;
  float4 s = {0.f, 0.f, 0.f, 0.f};
#pragma unroll
  for (int l = 0; l < CL; ++l) {
    float4 v = *(const float4*)(vp + (size_t)l * DIMS);
    s.x += v.x; s.y += v.y; s.z += v.z; s.w += v.w;
  }
  float* pp = part + ((size_t)b * DIMS + d0) * NC + c;
  pp[0 * NC] = s.x; pp[1 * NC] = s.y; pp[2 * NC] = s.z; pp[3 * NC] = s.w;
}

__global__ void chunk_scan(float* __restrict__ part) {
  const int g = blockIdx.x * blockDim.x + threadIdx.x;
  float* p = part + (size_t)g * NC;
  float run = 0.f;
#pragma unroll 4
  for (int c = 0; c < NC; ++c) {
    float t = p[c];
    p[c] = run;
    run += t;
  }
}

__global__ void cum_avg(const float* __restrict__ V,
                        const float* __restrict__ part,
                        unsigned short* __restrict__ avgB) {
  const int bc = blockIdx.x;
  const int b = bc >> 7;
  const int c = bc & (NC - 1);
  const int d0 = threadIdx.x * 4;
  const float* pp = part + ((size_t)b * DIMS + d0) * NC + c;
  float4 run = {pp[0 * NC], pp[1 * NC], pp[2 * NC], pp[3 * NC]};
  const float* vp = V + ((size_t)b * SEQ + (size_t)c * CL) * DIMS + d0;
  unsigned short* op = avgB + ((size_t)b * SEQ + (size_t)c * CL) * DIMS + d0;
#pragma unroll
  for (int l = 0; l < CL; ++l) {
    float4 v = *(const float4*)(vp + (size_t)l * DIMS);
    run.x += v.x; run.y += v.y; run.z += v.z; run.w += v.w;
    const float inv = 1.0f / (float)(c * CL + l + 1);
    ushort4 o = {f2bf(run.x * inv), f2bf(run.y * inv), f2bf(run.z * inv),
                 f2bf(run.w * inv)};
    *(ushort4*)(op + (size_t)l * DIMS) = o;
  }
}

// ---------- workspace layout (bytes, 256-aligned) ----------
#define WS_EB 0UL                   // bf16 [4096][1024]   8,388,608
#define WS_WV 8388608UL             // bf16 [1024][1024]   2,097,152
#define WS_WO 10485760UL            // bf16 [32000][1024] 65,536,000
#define WS_V 76021760UL             // f32  [4096][1024]  16,777,216
#define WS_AVG 92798976UL           // bf16 [4096][1024]   8,388,608
#define WS_PART 101187584UL         // f32  [2][1024][128] 1,048,576
#define WS_NEED 102236160UL

extern "C" void kernel_launch(void* const* d_in, const int* in_sizes, int n_in,
                              void* d_out, int out_size, void* d_ws,
                              size_t ws_size, hipStream_t stream) {
  const int* idx = (const int*)d_in[0];
  const float* emb = (const float*)d_in[1];
  const float* W_V = (const float*)d_in[2];
  const float* W_out = (const float*)d_in[3];
  const float* b_out = (const float*)d_in[4];
  float* out = (float*)d_out;

  if (ws_size < WS_NEED) return;

  char* ws = (char*)d_ws;
  unsigned short* eB = (unsigned short*)(ws + WS_EB);
  unsigned short* wvB = (unsigned short*)(ws + WS_WV);
  unsigned short* woB = (unsigned short*)(ws + WS_WO);
  float* V = (float*)(ws + WS_V);
  unsigned short* avgB = (unsigned short*)(ws + WS_AVG);
  float* part = (float*)(ws + WS_PART);

  hipLaunchKernelGGL(cvt_f32_bf16, dim3(1024), dim3(256), 0, stream, W_V, wvB,
                     (DIMS * DIMS) / 4);
  hipLaunchKernelGGL(cvt_f32_bf16, dim3(2048), dim3(256), 0, stream, W_out,
                     woB, (VOCAB * DIMS) / 4);
  hipLaunchKernelGGL(gather_emb, dim3(ROWS), dim3(256), 0, stream, idx, emb,
                     eB);
  // V = e @ W_V^T  (M=4096, N=1024, K=1024) — old 128^2 kernel, 256 blocks
  hipLaunchKernelGGL(gemm_bt, dim3(ROWS / 128, DIMS / 128), dim3(256), 0,
                     stream, eB, wvB, V, (const float*)nullptr, DIMS, DIMS);
  hipLaunchKernelGGL(chunk_sums, dim3(BATCH * NC), dim3(256), 0, stream, V,
                     part);
  hipLaunchKernelGGL(chunk_scan, dim3((BATCH * DIMS) / 256), dim3(256), 0,
                     stream, part);
  hipLaunchKernelGGL(cum_avg, dim3(BATCH * NC), dim3(256), 0, stream, V, part,
                     avgB);
  // out = avg @ W_out^T + b_out  (M=4096, N=32000, K=1024)
  // grid x = m-tiles (8, fastest): concurrent B working set small,
  // W_out streams once (round-2 counter evidence).
  hipLaunchKernelGGL(gemm512x128_bt, dim3(ROWS / 512, VOCAB / 128), dim3(512),
                     0, stream, avgB, woB, out, b_out, DIMS, VOCAB);
}

// Round 11
// 468.257 us; speedup vs baseline: 1.0742x; 1.0742x over previous
//
#include <hip/hip_runtime.h>
#include <hip/hip_bf16.h>

typedef __attribute__((ext_vector_type(4))) float f32x4;
typedef __attribute__((ext_vector_type(8))) short bf16x8;

#define VOCAB 32000
#define DIMS 1024
#define BATCH 2
#define SEQ 2048
#define ROWS (BATCH * SEQ)  // 4096
#define NC 128              // cumsum chunks per sequence
#define CL 16               // chunk length; NC*CL == SEQ

// ---------- helpers ----------
static __device__ __forceinline__ unsigned short f2bf(float f) {
  unsigned int u = __float_as_uint(f);
  unsigned int r = u + 0x7fffu + ((u >> 16) & 1u);
  return (unsigned short)(r >> 16);
}

// ---------- fp32 -> bf16 bulk convert ----------
__global__ void cvt_f32_bf16(const float* __restrict__ src,
                             unsigned short* __restrict__ dst, int n4) {
  int i = blockIdx.x * blockDim.x + threadIdx.x;
  int stride = gridDim.x * blockDim.x;
  for (; i < n4; i += stride) {
    float4 v = ((const float4*)src)[i];
    ushort4 o = {f2bf(v.x), f2bf(v.y), f2bf(v.z), f2bf(v.w)};
    ((ushort4*)dst)[i] = o;
  }
}

// ---------- embedding gather + convert ----------
__global__ void gather_emb(const int* __restrict__ idx,
                           const float* __restrict__ emb,
                           unsigned short* __restrict__ eB) {
  const int row = blockIdx.x;
  const int t = threadIdx.x;
  const int token = idx[row];
  const float4* src = (const float4*)(emb + (size_t)token * DIMS);
  float4 v = src[t];
  ushort4 o = {f2bf(v.x), f2bf(v.y), f2bf(v.z), f2bf(v.w)};
  ((ushort4*)(eB + (size_t)row * DIMS))[t] = o;
}

// ---------- old 128x128 NT GEMM (kept for the small V projection) ----------
__global__ __launch_bounds__(256) void gemm_bt(
    const unsigned short* __restrict__ A, const unsigned short* __restrict__ B,
    float* __restrict__ C, const float* __restrict__ bias, int K, int ldC) {
  __shared__ __align__(16) unsigned short sA[128 * 32];
  __shared__ __align__(16) unsigned short sB[128 * 32];

  const int tid = threadIdx.x;
  const int lane = tid & 63;
  const int w = tid >> 6;
  const int wr = w >> 1;
  const int wc = w & 1;
  const long mBase = (long)blockIdx.x * 128;
  const long nBase = (long)blockIdx.y * 128;

  const unsigned short* Ati = A + mBase * K;
  const unsigned short* Bti = B + nBase * K;

  const int srow0 = w * 32;
  const int sr = lane >> 2;
  const int ske = (lane & 3) * 8;

  f32x4 acc[4][4] = {};

  for (int kt = 0; kt < K; kt += 32) {
    __syncthreads();
#pragma unroll
    for (int i = 0; i < 2; ++i) {
      const int r = srow0 + i * 16;
      __builtin_amdgcn_global_load_lds(
          (const __attribute__((address_space(1))) unsigned int*)(
              Ati + (long)(r + sr) * K + kt + ske),
          (__attribute__((address_space(3))) unsigned int*)(&sA[r * 32]),
          16, 0, 0);
      __builtin_amdgcn_global_load_lds(
          (const __attribute__((address_space(1))) unsigned int*)(
              Bti + (long)(r + sr) * K + kt + ske),
          (__attribute__((address_space(3))) unsigned int*)(&sB[r * 32]),
          16, 0, 0);
    }
    __syncthreads();

    bf16x8 af[4], bfr[4];
#pragma unroll
    for (int mi = 0; mi < 4; ++mi)
      af[mi] = *(const bf16x8*)&sA[(wr * 64 + mi * 16 + (lane & 15)) * 32 +
                                   8 * (lane >> 4)];
#pragma unroll
    for (int ni = 0; ni < 4; ++ni)
      bfr[ni] = *(const bf16x8*)&sB[(wc * 64 + ni * 16 + (lane & 15)) * 32 +
                                    8 * (lane >> 4)];
#pragma unroll
    for (int mi = 0; mi < 4; ++mi)
#pragma unroll
      for (int ni = 0; ni < 4; ++ni)
        acc[mi][ni] = __builtin_amdgcn_mfma_f32_16x16x32_bf16(
            af[mi], bfr[ni], acc[mi][ni], 0, 0, 0);
  }

  const int rq = lane >> 4;
  const int cl = lane & 15;
#pragma unroll
  for (int ni = 0; ni < 4; ++ni) {
    const long c = nBase + wc * 64 + ni * 16 + cl;
    const float bv = bias ? bias[c] : 0.0f;
#pragma unroll
    for (int mi = 0; mi < 4; ++mi) {
      const long r = mBase + wr * 64 + mi * 16 + rq * 4;
#pragma unroll
      for (int j = 0; j < 4; ++j)
        C[(r + j) * (long)ldC + c] = acc[mi][ni][j] + bv;
    }
  }
}

// ---------- 256x128 tri-buffer single-barrier NT GEMM ----------
// ROUND 11: r8 (2 blocks/CU, dbuf, 2 barriers/window) = best at 349us/33%.
// The dbuf WAR (stage(t+2) overwrites the buffer being read in window t)
// is what forces the 2nd barrier. Tri-buffer removes it: stage(t+2) targets
// buf[(t+2)%3] == buf[(t-1)%3], whose readers finished before bar(t) (their
// frags were consumed by MFMA(t-1) under compiler lgkmcnt BEFORE those waves
// reached bar(t)). Window = ONE barrier:
//   { vmcnt(3) -> s_barrier -> stage(t+2) -> 8 frag reads -> 16 MFMA }
// Half the sync events of r8; stage issued at the earliest point.
// Geometry = r8 verbatim: BM=256 BN=128 BK=32, 8 waves (4m x 2n), wave-tile
// 64x64, LDS 3 x 24 KiB = 72 KiB -> still 2 blocks/CU. Hoisted per-lane
// global pointers (r10, VALU down). Swizzle = r4 involution (conflicts 0).
// Ledger (3 loads/wave/window): prologue {0,1}=6 out; window t entry 6 out,
// vmcnt(3) retires tile t (its 3 writes + barrier => all waves' writes
// visible). Tail t==NT-1: only own 3 outstanding -> vmcnt(0).
__global__ __launch_bounds__(512, 4) void gemm256x128_tri(
    const unsigned short* __restrict__ A,  // [M][K] bf16, K-contiguous
    const unsigned short* __restrict__ B,  // [N][K] bf16, K-contiguous
    float* __restrict__ C,                 // [M][ldC] fp32
    const float* __restrict__ bias,        // [>=N] fp32 or nullptr
    int K, int ldC) {
  __shared__ __align__(16) unsigned short lds[3][384 * 32];  // 72 KiB

  const int tid = threadIdx.x;
  const int lane = tid & 63;
  const int w = tid >> 6;  // wave 0..7
  const int wr = w >> 1;   // 0..3 -> A row-quarter
  const int wc = w & 1;    // 0..1 -> B col-half
  const long mBase = (long)blockIdx.x * 256;
  const long nBase = (long)blockIdx.y * 128;
  const int NT = K >> 5;  // BK=32 windows

  const int rl = lane & 15;
  const int koffR = ((lane >> 4) * 8) ^ (((rl >> 1) & 3) << 3);
  const int skel = ((lane & 3) * 8) ^ (((lane >> 3) & 3) << 3);

  // hoisted per-lane global source pointers (advance += 32 elems per stage)
  const unsigned short* ap0 =
      A + (mBase + 0 + w * 16 + (lane >> 2)) * (long)K + skel;
  const unsigned short* ap1 =
      A + (mBase + 128 + w * 16 + (lane >> 2)) * (long)K + skel;
  const unsigned short* bp =
      B + (nBase + w * 16 + (lane >> 2)) * (long)K + skel;

#define GL(p, d)                                                    \
  __builtin_amdgcn_global_load_lds(                                 \
      (const __attribute__((address_space(1))) unsigned int*)(p),   \
      (__attribute__((address_space(3))) unsigned int*)(d), 16, 0, 0)
#define STAGE_ALL(buf)                    \
  do {                                    \
    GL(ap0, (buf) + (0 + w * 16) * 32);   \
    GL(ap1, (buf) + (128 + w * 16) * 32); \
    GL(bp, (buf) + 8192 + w * 512);       \
    ap0 += 32; ap1 += 32; bp += 32;       \
  } while (0)
#define LDF(pl, r) (*(const bf16x8*)&(pl)[(r) * 32 + koffR])

  f32x4 acc[4][4] = {};

  // rotating buffer pointers (read / next / stage-target)
  unsigned short* bufR = lds[0];
  unsigned short* bufN = lds[1];
  unsigned short* bufS = lds[2];

  // ---- prologue: stage windows 0,1 (6 loads/wave outstanding) ----
  STAGE_ALL(bufR);
  STAGE_ALL(bufN);

  for (int t = 0; t < NT; ++t) {
    if (t == NT - 1)
      asm volatile("s_waitcnt vmcnt(0)" ::: "memory");
    else
      asm volatile("s_waitcnt vmcnt(3)" ::: "memory");
    __builtin_amdgcn_s_barrier();

    // earliest vmem issue: stage t+2 into the buffer read in window t-1
    if (t + 2 < NT) STAGE_ALL(bufS);

    const unsigned short* Ap = bufR;         // [256][32]
    const unsigned short* Bp = bufR + 8192;  // [128][32]
    bf16x8 a[4], b[4];
#pragma unroll
    for (int mi = 0; mi < 4; ++mi) a[mi] = LDF(Ap, wr * 64 + mi * 16 + rl);
#pragma unroll
    for (int ni = 0; ni < 4; ++ni) b[ni] = LDF(Bp, wc * 64 + ni * 16 + rl);

    __builtin_amdgcn_s_setprio(1);
#pragma unroll
    for (int mi = 0; mi < 4; ++mi)
#pragma unroll
      for (int ni = 0; ni < 4; ++ni)
        acc[mi][ni] = __builtin_amdgcn_mfma_f32_16x16x32_bf16(
            a[mi], b[ni], acc[mi][ni], 0, 0, 0);
    __builtin_amdgcn_s_setprio(0);

    // rotate: R <- N <- S <- R
    unsigned short* tmp = bufR;
    bufR = bufN;
    bufN = bufS;
    bufS = tmp;
  }
#undef LDF
#undef STAGE_ALL
#undef GL

  // ---- epilogue: C/D frag mapping col=lane&15, row=4*(lane>>4)+reg [m89] ----
  const int rq = lane >> 4;
  const int cl = lane & 15;
#pragma unroll
  for (int ni = 0; ni < 4; ++ni) {
    const long c = nBase + wc * 64 + ni * 16 + cl;
    const float bv = bias ? bias[c] : 0.0f;
#pragma unroll
    for (int mi = 0; mi < 4; ++mi) {
      const long r = mBase + wr * 64 + mi * 16 + rq * 4;
#pragma unroll
      for (int j = 0; j < 4; ++j)
        C[(r + j) * (long)ldC + c] = acc[mi][ni][j] + bv;
    }
  }
}

// ---------- causal cumulative mean (chunked scan) ----------
__global__ void chunk_sums(const float* __restrict__ V,
                           float* __restrict__ part) {
  const int bc = blockIdx.x;
  const int b = bc >> 7;
  const int c = bc & (NC - 1);
  const int d0 = threadIdx.x * 4;
  const float* vp = V + ((size_t)b * SEQ + (size_t)c * CL) * DIMS + d0;
  float4 s = {0.f, 0.f, 0.f, 0.f};
#pragma unroll
  for (int l = 0; l < CL; ++l) {
    float4 v = *(const float4*)(vp + (size_t)l * DIMS);
    s.x += v.x; s.y += v.y; s.z += v.z; s.w += v.w;
  }
  float* pp = part + ((size_t)b * DIMS + d0) * NC + c;
  pp[0 * NC] = s.x; pp[1 * NC] = s.y; pp[2 * NC] = s.z; pp[3 * NC] = s.w;
}

__global__ void chunk_scan(float* __restrict__ part) {
  const int g = blockIdx.x * blockDim.x + threadIdx.x;
  float* p = part + (size_t)g * NC;
  float run = 0.f;
#pragma unroll 4
  for (int c = 0; c < NC; ++c) {
    float t = p[c];
    p[c] = run;
    run += t;
  }
}

__global__ void cum_avg(const float* __restrict__ V,
                        const float* __restrict__ part,
                        unsigned short* __restrict__ avgB) {
  const int bc = blockIdx.x;
  const int b = bc >> 7;
  const int c = bc & (NC - 1);
  const int d0 = threadIdx.x * 4;
  const float* pp = part + ((size_t)b * DIMS + d0) * NC + c;
  float4 run = {pp[0 * NC], pp[1 * NC], pp[2 * NC], pp[3 * NC]};
  const float* vp = V + ((size_t)b * SEQ + (size_t)c * CL) * DIMS + d0;
  unsigned short* op = avgB + ((size_t)b * SEQ + (size_t)c * CL) * DIMS + d0;
#pragma unroll
  for (int l = 0; l < CL; ++l) {
    float4 v = *(const float4*)(vp + (size_t)l * DIMS);
    run.x += v.x; run.y += v.y; run.z += v.z; run.w += v.w;
    const float inv = 1.0f / (float)(c * CL + l + 1);
    ushort4 o = {f2bf(run.x * inv), f2bf(run.y * inv), f2bf(run.z * inv),
                 f2bf(run.w * inv)};
    *(ushort4*)(op + (size_t)l * DIMS) = o;
  }
}

// ---------- workspace layout (bytes, 256-aligned) ----------
#define WS_EB 0UL                   // bf16 [4096][1024]   8,388,608
#define WS_WV 8388608UL             // bf16 [1024][1024]   2,097,152
#define WS_WO 10485760UL            // bf16 [32000][1024] 65,536,000
#define WS_V 76021760UL             // f32  [4096][1024]  16,777,216
#define WS_AVG 92798976UL           // bf16 [4096][1024]   8,388,608
#define WS_PART 101187584UL         // f32  [2][1024][128] 1,048,576
#define WS_NEED 102236160UL

extern "C" void kernel_launch(void* const* d_in, const int* in_sizes, int n_in,
                              void* d_out, int out_size, void* d_ws,
                              size_t ws_size, hipStream_t stream) {
  const int* idx = (const int*)d_in[0];
  const float* emb = (const float*)d_in[1];
  const float* W_V = (const float*)d_in[2];
  const float* W_out = (const float*)d_in[3];
  const float* b_out = (const float*)d_in[4];
  float* out = (float*)d_out;

  if (ws_size < WS_NEED) return;

  char* ws = (char*)d_ws;
  unsigned short* eB = (unsigned short*)(ws + WS_EB);
  unsigned short* wvB = (unsigned short*)(ws + WS_WV);
  unsigned short* woB = (unsigned short*)(ws + WS_WO);
  float* V = (float*)(ws + WS_V);
  unsigned short* avgB = (unsigned short*)(ws + WS_AVG);
  float* part = (float*)(ws + WS_PART);

  hipLaunchKernelGGL(cvt_f32_bf16, dim3(1024), dim3(256), 0, stream, W_V, wvB,
                     (DIMS * DIMS) / 4);
  hipLaunchKernelGGL(cvt_f32_bf16, dim3(2048), dim3(256), 0, stream, W_out,
                     woB, (VOCAB * DIMS) / 4);
  hipLaunchKernelGGL(gather_emb, dim3(ROWS), dim3(256), 0, stream, idx, emb,
                     eB);
  // V = e @ W_V^T  (M=4096, N=1024, K=1024) — old 128^2 kernel, 256 blocks
  hipLaunchKernelGGL(gemm_bt, dim3(ROWS / 128, DIMS / 128), dim3(256), 0,
                     stream, eB, wvB, V, (const float*)nullptr, DIMS, DIMS);
  hipLaunchKernelGGL(chunk_sums, dim3(BATCH * NC), dim3(256), 0, stream, V,
                     part);
  hipLaunchKernelGGL(chunk_scan, dim3((BATCH * DIMS) / 256), dim3(256), 0,
                     stream, part);
  hipLaunchKernelGGL(cum_avg, dim3(BATCH * NC), dim3(256), 0, stream, V, part,
                     avgB);
  // out = avg @ W_out^T + b_out  (M=4096, N=32000, K=1024)
  // grid x = m-tiles (16, fastest): concurrent B working set small,
  // W_out streams once (round-2 counter evidence).
  hipLaunchKernelGGL(gemm256x128_tri, dim3(ROWS / 256, VOCAB / 128), dim3(512),
                     0, stream, avgB, woB, out, b_out, DIMS, VOCAB);
}